// Round 10
// baseline (935.660 us; speedup 1.0000x reference)
//
#include <hip/hip_runtime.h>

typedef __attribute__((ext_vector_type(8))) short bf16x8;
typedef __attribute__((ext_vector_type(4))) float f32x4;

#define MFMA16 __builtin_amdgcn_mfma_f32_16x16x32_bf16

__device__ __forceinline__ float fexp2(float x) {
#if __has_builtin(__builtin_amdgcn_exp2f)
    return __builtin_amdgcn_exp2f(x);
#else
    return __expf(x * 0.6931471805599453f);
#endif
}

__device__ __forceinline__ short f2bf(float f) {
    union { float f; unsigned u; } v; v.f = f;
    unsigned r = v.u + 0x7fffu + ((v.u >> 16) & 1u);
    return (short)(r >> 16);
}

__device__ __forceinline__ void gl_lds16(const short* g, short* l) {
    __builtin_amdgcn_global_load_lds(
        (const __attribute__((address_space(1))) unsigned int*)g,
        (__attribute__((address_space(3))) unsigned int*)l, 16, 0, 0);
}

// ---------------- cast hidden fp32 -> bf16 ----------------
__global__ __launch_bounds__(256) void cast_hidden(const float* __restrict__ src,
                                                   short* __restrict__ dst, int n) {
    int i = (blockIdx.x * 256 + threadIdx.x) * 4;
    if (i < n) {
        float4 f = *(const float4*)(src + i);
        short4 o = make_short4(f2bf(f.x), f2bf(f.y), f2bf(f.z), f2bf(f.w));
        *(short4*)(dst + i) = o;
    }
}

// ---------------- transpose+cast weight [1024][1024] fp32 -> WT bf16 [n][k] ----------------
__global__ __launch_bounds__(256) void transpose_cast(const float* __restrict__ src,
                                                      short* __restrict__ dst) {
    __shared__ float tile[32][33];
    int tx = threadIdx.x, ty = threadIdx.y;          // 32 x 8
    int bx = blockIdx.x * 32, by = blockIdx.y * 32;  // bx: n-tile, by: k-tile
#pragma unroll
    for (int i = 0; i < 4; ++i)
        tile[ty + i * 8][tx] = src[(size_t)(by + ty + i * 8) * 1024 + bx + tx];
    __syncthreads();
#pragma unroll
    for (int i = 0; i < 4; ++i)
        dst[(size_t)(bx + ty + i * 8) * 1024 + by + tx] = f2bf(tile[tx][ty + i * 8]);
}

// ---------------- relative-position bias table (pre-scaled by log2(e)): tab[h][d+2047] ----------------
__global__ __launch_bounds__(256) void build_bias(const float* __restrict__ relb,
                                                  float* __restrict__ tab) {
    int d = blockIdx.x * 256 + threadIdx.x;  // 0..4094
    if (d < 4095) {
        int rel = d - 2047;
        int rp = rel < 0 ? -rel : rel;
        int bucket;
        if (rp < 8)
            bucket = rp;
        else
            bucket = 8 + (rp >= 12) + (rp >= 16) + (rp >= 23) + (rp >= 32) +
                     (rp >= 46) + (rp >= 64) + (rp >= 91);
        if (rel > 0) bucket += 16;
#pragma unroll
        for (int hh = 0; hh < 16; ++hh)
            tab[hh * 4095 + d] = relb[bucket * 16 + hh] * 1.4426950408889634f;
    }
}

// ---------------- 128x128 bf16 MFMA GEMM: C = A[M,K] @ WT[n][k]^T ----------------
__global__ __launch_bounds__(256) void gemm128(const short* __restrict__ A,
                                               const short* __restrict__ BT, int Kdim,
                                               int mode, short* __restrict__ qb,
                                               short* __restrict__ kb,
                                               short* __restrict__ vtb,
                                               float* __restrict__ fout) {
    __shared__ short As[128 * 32];
    __shared__ short Bs[128 * 32];
    const int tid = threadIdx.x, wave = tid >> 6, lane = tid & 63;
    const int quad = lane >> 4, col = lane & 15;
    const int wm = wave >> 1, wn = wave & 1;
    const int m0 = blockIdx.x * 128, n0 = blockIdx.y * 128;

    f32x4 zero4 = {0.f, 0.f, 0.f, 0.f};
    f32x4 acc[4][4];
#pragma unroll
    for (int i = 0; i < 4; ++i)
#pragma unroll
        for (int j = 0; j < 4; ++j) acc[i][j] = zero4;

    const int nk = Kdim >> 5;
    for (int kk = 0; kk < nk; ++kk) {
        __syncthreads();
#pragma unroll
        for (int c = 0; c < 2; ++c) {
            int L = c * 256 + wave * 64 + lane;
            int row = L >> 2, c4 = L & 3;
            int gc = c4 ^ ((row >> 1) & 3);
            gl_lds16(A + (size_t)(m0 + row) * Kdim + kk * 32 + gc * 8,
                     &As[(c * 256 + wave * 64) * 8]);
            gl_lds16(BT + (size_t)(n0 + row) * Kdim + kk * 32 + gc * 8,
                     &Bs[(c * 256 + wave * 64) * 8]);
        }
        __syncthreads();
        bf16x8 af[4], bfr[4];
#pragma unroll
        for (int i = 0; i < 4; ++i) {
            int ra = wm * 64 + i * 16 + col;
            af[i] = *(const bf16x8*)(&As[ra * 32 + (quad ^ ((ra >> 1) & 3)) * 8]);
            int rb = wn * 64 + i * 16 + col;
            bfr[i] = *(const bf16x8*)(&Bs[rb * 32 + (quad ^ ((rb >> 1) & 3)) * 8]);
        }
#pragma unroll
        for (int mi = 0; mi < 4; ++mi)
#pragma unroll
            for (int ni = 0; ni < 4; ++ni)
                acc[mi][ni] = MFMA16(af[mi], bfr[ni], acc[mi][ni], 0, 0, 0);
    }

#pragma unroll
    for (int mi = 0; mi < 4; ++mi) {
#pragma unroll
        for (int ni = 0; ni < 4; ++ni) {
#pragma unroll
            for (int r = 0; r < 4; ++r) {
                int gm = m0 + wm * 64 + mi * 16 + quad * 4 + r;
                int gn = n0 + wn * 64 + ni * 16 + col;
                float v = acc[mi][ni][r];
                if (mode == 1) {
                    fout[(size_t)gm * 1024 + gn] = v;
                } else {
                    int widx = gn >> 10, nn = gn & 1023;
                    int hh = nn >> 6, dk = nn & 63;
                    int bb = gm >> 11, ss = gm & 2047;
                    size_t bh = (size_t)(bb * 16 + hh);
                    if (widx == 0)
                        qb[(bh * 2048 + ss) * 64 + dk] = f2bf(v);
                    else if (widx == 1)
                        kb[(bh * 2048 + ss) * 64 + dk] = f2bf(v);
                    else
                        vtb[(bh * 64 + dk) * 2048 + ss] = f2bf(v);
                }
            }
        }
    }
}

// ---------------- fused attention: barrier-free, K/V direct from L1/L2 ----------------
// K/V per (b,h) = 512KB; XCD-chunked swizzle keeps each XCD's active K/V set
// (4 groups = 2MB) resident in its 4MB private L2 -> LDS staging is pure
// overhead (m169 lesson). Zero __syncthreads in this kernel.
// Softmax uses fixed shift M0=0 (exact identity): p = exp2(s*log2e+b2 - log2(l)),
// |s*log2e| << 126 so no overflow; kills the fmax chain + sv[32] buffer.
__global__ __launch_bounds__(256) void attn_kernel(const short* __restrict__ qbuf,
                                                   const short* __restrict__ kbuf,
                                                   const short* __restrict__ vtbuf,
                                                   const float* __restrict__ bias_tab,
                                                   float* __restrict__ attn_out,
                                                   short* __restrict__ ctxbuf) {
    __shared__ short Pt[4][640];  // per-wave [16 q][32 k] bf16, row stride 40 (wave-private)

    const int tid = threadIdx.x;
    const int wave = tid >> 6, lane = tid & 63;
    const int quad = lane >> 4, col = lane & 15;

    // XCD-chunked swizzle (T1): 1024 blocks, 8 XCDs -> each XCD gets 128
    // consecutive logical blocks = 4 whole (b,h) groups.
    const int raw = blockIdx.x;
    const int blk = (raw & 7) * 128 + (raw >> 3);
    const int qt = blk & 31, h = (blk >> 5) & 15, b = blk >> 9;
    const int q0 = qt * 64 + wave * 16;

    const size_t bh = (size_t)(b * 16 + h);
    const short* Kh = kbuf + bh * 2048 * 64;
    const short* VTh = vtbuf + bh * 64 * 2048;
    const short* Qh = qbuf + bh * 2048 * 64;
    const float* btab = bias_tab + h * 4095;
    const float L2E = 1.4426950408889634f;

    bf16x8 aq0 = *(const bf16x8*)(Qh + (q0 + col) * 64 + quad * 8);
    bf16x8 aq1 = *(const bf16x8*)(Qh + (q0 + col) * 64 + 32 + quad * 8);

    // ---------- pass A: denom l = sum exp2(s*log2e + b2), fixed shift M0=0 ----------
    // lane (quad,col): q = q0+col, keys {st*16 + quad*4 + r}
    float l = 0.f;
    for (int kt = 0; kt < 16; ++kt) {
        const short* Kt = Kh + kt * 128 * 64;
        const float* bp = btab + (kt * 128 - (q0 + col) + 2047 + quad * 4);
#pragma unroll
        for (int st = 0; st < 8; ++st) {
            int krow = st * 16 + col;
            bf16x8 bk0 = *(const bf16x8*)(Kt + krow * 64 + quad * 8);
            bf16x8 bk1 = *(const bf16x8*)(Kt + krow * 64 + 32 + quad * 8);
            f32x4 acc = {0.f, 0.f, 0.f, 0.f};
            acc = MFMA16(bk0, aq0, acc, 0, 0, 0);  // swapped: C[k][q]
            acc = MFMA16(bk1, aq1, acc, 0, 0, 0);
#pragma unroll
            for (int r = 0; r < 4; ++r)
                l += fexp2(fmaf(acc[r], L2E, bp[st * 16 + r]));
        }
    }
    // merge partial l across the 4 quads holding the same q = q0 + col
    l += __shfl_xor(l, 16);
    l += __shfl_xor(l, 32);
    const float moff = __log2f(l);  // p = exp2(s*log2e + bias2 - moff)

    // ---------- pass B: probs out (f32x4 nt stores) + PV, no staging ----------
    f32x4 zero4 = {0.f, 0.f, 0.f, 0.f};
    f32x4 ctx[4];
#pragma unroll
    for (int dt = 0; dt < 4; ++dt) ctx[dt] = zero4;

    for (int kt = 0; kt < 16; ++kt) {
        const short* Kt = Kh + kt * 128 * 64;
        const short* Vt = VTh + kt * 128;
        const float* bp = btab + (kt * 128 - (q0 + col) + 2047 + quad * 4);
        float* aout = attn_out + ((bh * 2048 + q0 + col) * 2048 + kt * 128 + quad * 4);
        __builtin_amdgcn_s_setprio(1);  // T5: favor the MFMA-dense cluster
#pragma unroll
        for (int pr = 0; pr < 4; ++pr) {  // 32-key groups
#pragma unroll
            for (int hf = 0; hf < 2; ++hf) {
                int st = pr * 2 + hf;
                int krow = st * 16 + col;
                bf16x8 bk0 = *(const bf16x8*)(Kt + krow * 64 + quad * 8);
                bf16x8 bk1 = *(const bf16x8*)(Kt + krow * 64 + 32 + quad * 8);
                f32x4 acc = {0.f, 0.f, 0.f, 0.f};
                acc = MFMA16(bk0, aq0, acc, 0, 0, 0);  // swapped: C[k][q]
                acc = MFMA16(bk1, aq1, acc, 0, 0, 0);
                f32x4 pv;   // ext_vector type: valid for __builtin_nontemporal_store
                short4 pb;
#pragma unroll
                for (int r = 0; r < 4; ++r) {
                    float p = fexp2(fmaf(acc[r], L2E, bp[st * 16 + r]) - moff);
                    pv[r] = p;
                    ((short*)&pb)[r] = f2bf(p);
                }
                __builtin_nontemporal_store(pv, (f32x4*)(aout + st * 16));
                *(short4*)(&Pt[wave][col * 40 + hf * 16 + quad * 4]) = pb;
            }
            bf16x8 ap = *(const bf16x8*)(&Pt[wave][col * 40 + quad * 8]);
#pragma unroll
            for (int dt = 0; dt < 4; ++dt) {
                int vrow = dt * 16 + col;
                bf16x8 bv = *(const bf16x8*)(Vt + (size_t)vrow * 2048 + (pr * 4 + quad) * 8);
                ctx[dt] = MFMA16(ap, bv, ctx[dt], 0, 0, 0);  // C[q][d]
            }
        }
        __builtin_amdgcn_s_setprio(0);
    }
#pragma unroll
    for (int dt = 0; dt < 4; ++dt)
#pragma unroll
        for (int r = 0; r < 4; ++r) {
            int q = q0 + quad * 4 + r;
            ctxbuf[((size_t)(b * 2048 + q)) * 1024 + h * 64 + dt * 16 + col] =
                f2bf(ctx[dt][r]);
        }
}

extern "C" void kernel_launch(void* const* d_in, const int* in_sizes, int n_in,
                              void* d_out, int out_size, void* d_ws, size_t ws_size,
                              hipStream_t stream) {
    const float* hs = (const float*)d_in[0];
    const float* wq = (const float*)d_in[1];
    const float* wk = (const float*)d_in[2];
    const float* wv = (const float*)d_in[3];
    const float* wo = (const float*)d_in[4];
    const float* rb = (const float*)d_in[5];
    float* out = (float*)d_out;

    char* ws = (char*)d_ws;
    short* hsb  = (short*)(ws);                          // 8 MB  [4096][1024] bf16
    short* wt   = (short*)(ws + ((size_t)8 << 20));      // 6 MB  [3072][1024] bf16 (wq^T|wk^T|wv^T)
    short* wot  = (short*)(ws + ((size_t)14 << 20));     // 2 MB  [1024][1024] bf16
    short* qb   = (short*)(ws + ((size_t)16 << 20));     // 8 MB  [b,h,s,dk]
    short* kb   = (short*)(ws + ((size_t)24 << 20));     // 8 MB  [b,h,s,dk]
    short* vtb  = (short*)(ws + ((size_t)32 << 20));     // 8 MB  [b,h,dk,s]
    short* ctxb = (short*)(ws + ((size_t)40 << 20));     // 8 MB  [4096][1024]
    float* btab = (float*)(ws + ((size_t)48 << 20));     // 262 KB [16][4095] (log2e-scaled)

    cast_hidden<<<4096, 256, 0, stream>>>(hs, hsb, 4096 * 1024);
    dim3 tb(32, 8);
    transpose_cast<<<dim3(32, 32), tb, 0, stream>>>(wq, wt);
    transpose_cast<<<dim3(32, 32), tb, 0, stream>>>(wk, wt + (1u << 20));
    transpose_cast<<<dim3(32, 32), tb, 0, stream>>>(wv, wt + (2u << 20));
    transpose_cast<<<dim3(32, 32), tb, 0, stream>>>(wo, wot);
    build_bias<<<16, 256, 0, stream>>>(rb, btab);

    gemm128<<<dim3(32, 24), 256, 0, stream>>>(hsb, wt, 1024, 0, qb, kb, vtb, nullptr);
    attn_kernel<<<1024, 256, 0, stream>>>(qb, kb, vtb, btab, out + 4194304, ctxb);
    gemm128<<<dim3(32, 8), 256, 0, stream>>>(ctxb, wot, 1024, 1, nullptr, nullptr, nullptr, out);
}

// Round 11
// 747.385 us; speedup vs baseline: 1.2519x; 1.2519x over previous
//
#include <hip/hip_runtime.h>

typedef __attribute__((ext_vector_type(8))) short bf16x8;
typedef __attribute__((ext_vector_type(4))) float f32x4;

#define MFMA16 __builtin_amdgcn_mfma_f32_16x16x32_bf16

__device__ __forceinline__ float fexp2(float x) {
#if __has_builtin(__builtin_amdgcn_exp2f)
    return __builtin_amdgcn_exp2f(x);
#else
    return __expf(x * 0.6931471805599453f);
#endif
}

__device__ __forceinline__ short f2bf(float f) {
    union { float f; unsigned u; } v; v.f = f;
    unsigned r = v.u + 0x7fffu + ((v.u >> 16) & 1u);
    return (short)(r >> 16);
}

__device__ __forceinline__ void gl_lds16(const short* g, short* l) {
    __builtin_amdgcn_global_load_lds(
        (const __attribute__((address_space(1))) unsigned int*)g,
        (__attribute__((address_space(3))) unsigned int*)l, 16, 0, 0);
}

// ---------------- cast hidden fp32 -> bf16 ----------------
__global__ __launch_bounds__(256) void cast_hidden(const float* __restrict__ src,
                                                   short* __restrict__ dst, int n) {
    int i = (blockIdx.x * 256 + threadIdx.x) * 4;
    if (i < n) {
        float4 f = *(const float4*)(src + i);
        short4 o = make_short4(f2bf(f.x), f2bf(f.y), f2bf(f.z), f2bf(f.w));
        *(short4*)(dst + i) = o;
    }
}

// ---------------- transpose+cast weight [1024][1024] fp32 -> WT bf16 [n][k] ----------------
__global__ __launch_bounds__(256) void transpose_cast(const float* __restrict__ src,
                                                      short* __restrict__ dst) {
    __shared__ float tile[32][33];
    int tx = threadIdx.x, ty = threadIdx.y;          // 32 x 8
    int bx = blockIdx.x * 32, by = blockIdx.y * 32;  // bx: n-tile, by: k-tile
#pragma unroll
    for (int i = 0; i < 4; ++i)
        tile[ty + i * 8][tx] = src[(size_t)(by + ty + i * 8) * 1024 + bx + tx];
    __syncthreads();
#pragma unroll
    for (int i = 0; i < 4; ++i)
        dst[(size_t)(bx + ty + i * 8) * 1024 + by + tx] = f2bf(tile[tx][ty + i * 8]);
}

// ---------------- relative-position bias table (pre-scaled by log2(e)): tab[h][d+2047] ----------------
__global__ __launch_bounds__(256) void build_bias(const float* __restrict__ relb,
                                                  float* __restrict__ tab) {
    int d = blockIdx.x * 256 + threadIdx.x;  // 0..4094
    if (d < 4095) {
        int rel = d - 2047;
        int rp = rel < 0 ? -rel : rel;
        int bucket;
        if (rp < 8)
            bucket = rp;
        else
            bucket = 8 + (rp >= 12) + (rp >= 16) + (rp >= 23) + (rp >= 32) +
                     (rp >= 46) + (rp >= 64) + (rp >= 91);
        if (rel > 0) bucket += 16;
#pragma unroll
        for (int hh = 0; hh < 16; ++hh)
            tab[hh * 4095 + d] = relb[bucket * 16 + hh] * 1.4426950408889634f;
    }
}

// ---------------- 128x128 bf16 MFMA GEMM: C = A[M,K] @ WT[n][k]^T ----------------
__global__ __launch_bounds__(256) void gemm128(const short* __restrict__ A,
                                               const short* __restrict__ BT, int Kdim,
                                               int mode, short* __restrict__ qb,
                                               short* __restrict__ kb,
                                               short* __restrict__ vtb,
                                               float* __restrict__ fout) {
    __shared__ short As[128 * 32];
    __shared__ short Bs[128 * 32];
    const int tid = threadIdx.x, wave = tid >> 6, lane = tid & 63;
    const int quad = lane >> 4, col = lane & 15;
    const int wm = wave >> 1, wn = wave & 1;
    const int m0 = blockIdx.x * 128, n0 = blockIdx.y * 128;

    f32x4 zero4 = {0.f, 0.f, 0.f, 0.f};
    f32x4 acc[4][4];
#pragma unroll
    for (int i = 0; i < 4; ++i)
#pragma unroll
        for (int j = 0; j < 4; ++j) acc[i][j] = zero4;

    const int nk = Kdim >> 5;
    for (int kk = 0; kk < nk; ++kk) {
        __syncthreads();
#pragma unroll
        for (int c = 0; c < 2; ++c) {
            int L = c * 256 + wave * 64 + lane;
            int row = L >> 2, c4 = L & 3;
            int gc = c4 ^ ((row >> 1) & 3);
            gl_lds16(A + (size_t)(m0 + row) * Kdim + kk * 32 + gc * 8,
                     &As[(c * 256 + wave * 64) * 8]);
            gl_lds16(BT + (size_t)(n0 + row) * Kdim + kk * 32 + gc * 8,
                     &Bs[(c * 256 + wave * 64) * 8]);
        }
        __syncthreads();
        bf16x8 af[4], bfr[4];
#pragma unroll
        for (int i = 0; i < 4; ++i) {
            int ra = wm * 64 + i * 16 + col;
            af[i] = *(const bf16x8*)(&As[ra * 32 + (quad ^ ((ra >> 1) & 3)) * 8]);
            int rb = wn * 64 + i * 16 + col;
            bfr[i] = *(const bf16x8*)(&Bs[rb * 32 + (quad ^ ((rb >> 1) & 3)) * 8]);
        }
#pragma unroll
        for (int mi = 0; mi < 4; ++mi)
#pragma unroll
            for (int ni = 0; ni < 4; ++ni)
                acc[mi][ni] = MFMA16(af[mi], bfr[ni], acc[mi][ni], 0, 0, 0);
    }

#pragma unroll
    for (int mi = 0; mi < 4; ++mi) {
#pragma unroll
        for (int ni = 0; ni < 4; ++ni) {
#pragma unroll
            for (int r = 0; r < 4; ++r) {
                int gm = m0 + wm * 64 + mi * 16 + quad * 4 + r;
                int gn = n0 + wn * 64 + ni * 16 + col;
                float v = acc[mi][ni][r];
                if (mode == 1) {
                    fout[(size_t)gm * 1024 + gn] = v;
                } else {
                    int widx = gn >> 10, nn = gn & 1023;
                    int hh = nn >> 6, dk = nn & 63;
                    int bb = gm >> 11, ss = gm & 2047;
                    size_t bh = (size_t)(bb * 16 + hh);
                    if (widx == 0)
                        qb[(bh * 2048 + ss) * 64 + dk] = f2bf(v);
                    else if (widx == 1)
                        kb[(bh * 2048 + ss) * 64 + dk] = f2bf(v);
                    else
                        vtb[(bh * 64 + dk) * 2048 + ss] = f2bf(v);
                }
            }
        }
    }
}

// ---------------- fused attention: LDS-staged K/V, lane-local softmax, plain L2 stores ----------------
// Staging rationale (R10 profile): de-staged K reads = ~9GB L2 traffic (260µs at L2
// ceiling); staging reads each tile once per block. NT stores scattered 64B to HBM
// (1.5TB/s effective) -> plain stores let L2 write-combine st-adjacent 16B pieces.
__global__ __launch_bounds__(256) void attn_kernel(const short* __restrict__ qbuf,
                                                   const short* __restrict__ kbuf,
                                                   const short* __restrict__ vtbuf,
                                                   const float* __restrict__ bias_tab,
                                                   float* __restrict__ attn_out,
                                                   short* __restrict__ ctxbuf) {
    __shared__ short Ks[128 * 64];    // [key][dk], 16B chunks swizzled by (key&7)
    __shared__ short Vts[64 * 128];   // [dk][key] in pass B; second K buffer in pass A
    __shared__ short Pt[4][640];      // per-wave [16 q][32 k] bf16, row stride 40

    const int tid = threadIdx.x;
    const int wave = tid >> 6, lane = tid & 63;
    const int quad = lane >> 4, col = lane & 15;

    // XCD-chunked swizzle (T1): 1024 blocks, 8 XCDs.
    const int raw = blockIdx.x;
    const int blk = (raw & 7) * 128 + (raw >> 3);
    const int qt = blk & 31, h = (blk >> 5) & 15, b = blk >> 9;
    const int q0 = qt * 64 + wave * 16;

    const size_t bh = (size_t)(b * 16 + h);
    const short* Kh = kbuf + bh * 2048 * 64;
    const short* VTh = vtbuf + bh * 64 * 2048;
    const short* Qh = qbuf + bh * 2048 * 64;
    const float* btab = bias_tab + h * 4095;
    const float L2E = 1.4426950408889634f;

    bf16x8 aq0 = *(const bf16x8*)(Qh + (q0 + col) * 64 + quad * 8);
    bf16x8 aq1 = *(const bf16x8*)(Qh + (q0 + col) * 64 + 32 + quad * 8);

    // ---------- pass A: denom l (fixed shift M0=0, exact identity), K ping-pong ----------
    // lane (quad,col): q = q0+col, keys {st*16 + quad*4 + r}
    float l = 0.f;
    {
#pragma unroll
        for (int c = 0; c < 4; ++c) {  // prologue: stage kt=0 into Ks
            int L = c * 256 + wave * 64 + lane;
            int row = L >> 3, gc = (L & 7) ^ (row & 7);
            gl_lds16(Kh + (size_t)row * 64 + gc * 8, &Ks[(c * 256 + wave * 64) * 8]);
        }
        for (int kt = 0; kt < 16; ++kt) {
            __syncthreads();  // staging for kt complete; prev compute done
            short* cur = (kt & 1) ? Vts : Ks;
            if (kt < 15) {
                short* nxt = (kt & 1) ? Ks : Vts;
#pragma unroll
                for (int c = 0; c < 4; ++c) {
                    int L = c * 256 + wave * 64 + lane;
                    int row = L >> 3, gc = (L & 7) ^ (row & 7);
                    gl_lds16(Kh + (size_t)((kt + 1) * 128 + row) * 64 + gc * 8,
                             &nxt[(c * 256 + wave * 64) * 8]);
                }
            }
            const float* bp = btab + (kt * 128 - (q0 + col) + 2047 + quad * 4);
            __builtin_amdgcn_s_setprio(1);  // T5
#pragma unroll
            for (int st = 0; st < 8; ++st) {
                int krow = st * 16 + col;
                bf16x8 bk0 = *(const bf16x8*)(&cur[krow * 64 + (quad ^ (krow & 7)) * 8]);
                bf16x8 bk1 = *(const bf16x8*)(&cur[krow * 64 + ((4 + quad) ^ (krow & 7)) * 8]);
                f32x4 acc = {0.f, 0.f, 0.f, 0.f};
                acc = MFMA16(bk0, aq0, acc, 0, 0, 0);  // swapped: C[k][q]
                acc = MFMA16(bk1, aq1, acc, 0, 0, 0);
#pragma unroll
                for (int r = 0; r < 4; ++r)
                    l += fexp2(fmaf(acc[r], L2E, bp[st * 16 + r]));
            }
            __builtin_amdgcn_s_setprio(0);
        }
    }
    // merge partial l across the 4 quads holding the same q = q0 + col
    l += __shfl_xor(l, 16);
    l += __shfl_xor(l, 32);
    const float moff = __log2f(l);  // p = exp2(s*log2e + bias2 - moff)

    // ---------- pass B: probs out (plain f32x4 stores, L2 write-combined) + PV ----------
    f32x4 zero4 = {0.f, 0.f, 0.f, 0.f};
    f32x4 ctx[4];
#pragma unroll
    for (int dt = 0; dt < 4; ++dt) ctx[dt] = zero4;

    for (int kt = 0; kt < 16; ++kt) {
        __syncthreads();
#pragma unroll
        for (int c = 0; c < 4; ++c) {
            int L = c * 256 + wave * 64 + lane;
            int row = L >> 3, gc = (L & 7) ^ (row & 7);
            gl_lds16(Kh + (size_t)(kt * 128 + row) * 64 + gc * 8,
                     &Ks[(c * 256 + wave * 64) * 8]);
        }
#pragma unroll
        for (int c = 0; c < 4; ++c) {
            int L = c * 256 + wave * 64 + lane;
            int row = L >> 4, gc = (L & 15) ^ (row & 7);
            gl_lds16(VTh + (size_t)row * 2048 + kt * 128 + gc * 8,
                     &Vts[(c * 256 + wave * 64) * 8]);
        }
        __syncthreads();
        const float* bp = btab + (kt * 128 - (q0 + col) + 2047 + quad * 4);
        float* aout = attn_out + ((bh * 2048 + q0 + col) * 2048 + kt * 128 + quad * 4);
        __builtin_amdgcn_s_setprio(1);  // T5
#pragma unroll
        for (int pr = 0; pr < 4; ++pr) {  // 32-key groups
#pragma unroll
            for (int hf = 0; hf < 2; ++hf) {
                int st = pr * 2 + hf;
                int krow = st * 16 + col;
                bf16x8 bk0 = *(const bf16x8*)(&Ks[krow * 64 + (quad ^ (krow & 7)) * 8]);
                bf16x8 bk1 = *(const bf16x8*)(&Ks[krow * 64 + ((4 + quad) ^ (krow & 7)) * 8]);
                f32x4 acc = {0.f, 0.f, 0.f, 0.f};
                acc = MFMA16(bk0, aq0, acc, 0, 0, 0);  // swapped: C[k][q]
                acc = MFMA16(bk1, aq1, acc, 0, 0, 0);
                f32x4 pv;
                short4 pb;
#pragma unroll
                for (int r = 0; r < 4; ++r) {
                    float p = fexp2(fmaf(acc[r], L2E, bp[st * 16 + r]) - moff);
                    pv[r] = p;
                    ((short*)&pb)[r] = f2bf(p);
                }
                *(f32x4*)(aout + st * 16) = pv;  // plain store: L2 write-combining
                *(short4*)(&Pt[wave][col * 40 + hf * 16 + quad * 4]) = pb;
            }
            bf16x8 ap = *(const bf16x8*)(&Pt[wave][col * 40 + quad * 8]);
#pragma unroll
            for (int dt = 0; dt < 4; ++dt) {
                int vrow = dt * 16 + col;
                bf16x8 bv = *(const bf16x8*)(&Vts[vrow * 128 + ((pr * 4 + quad) ^ (vrow & 7)) * 8]);
                ctx[dt] = MFMA16(ap, bv, ctx[dt], 0, 0, 0);  // C[q][d]
            }
        }
        __builtin_amdgcn_s_setprio(0);
    }
#pragma unroll
    for (int dt = 0; dt < 4; ++dt)
#pragma unroll
        for (int r = 0; r < 4; ++r) {
            int q = q0 + quad * 4 + r;
            ctxbuf[((size_t)(b * 2048 + q)) * 1024 + h * 64 + dt * 16 + col] =
                f2bf(ctx[dt][r]);
        }
}

extern "C" void kernel_launch(void* const* d_in, const int* in_sizes, int n_in,
                              void* d_out, int out_size, void* d_ws, size_t ws_size,
                              hipStream_t stream) {
    const float* hs = (const float*)d_in[0];
    const float* wq = (const float*)d_in[1];
    const float* wk = (const float*)d_in[2];
    const float* wv = (const float*)d_in[3];
    const float* wo = (const float*)d_in[4];
    const float* rb = (const float*)d_in[5];
    float* out = (float*)d_out;

    char* ws = (char*)d_ws;
    short* hsb  = (short*)(ws);                          // 8 MB  [4096][1024] bf16
    short* wt   = (short*)(ws + ((size_t)8 << 20));      // 6 MB  [3072][1024] bf16 (wq^T|wk^T|wv^T)
    short* wot  = (short*)(ws + ((size_t)14 << 20));     // 2 MB  [1024][1024] bf16
    short* qb   = (short*)(ws + ((size_t)16 << 20));     // 8 MB  [b,h,s,dk]
    short* kb   = (short*)(ws + ((size_t)24 << 20));     // 8 MB  [b,h,s,dk]
    short* vtb  = (short*)(ws + ((size_t)32 << 20));     // 8 MB  [b,h,dk,s]
    short* ctxb = (short*)(ws + ((size_t)40 << 20));     // 8 MB  [4096][1024]
    float* btab = (float*)(ws + ((size_t)48 << 20));     // 262 KB [16][4095] (log2e-scaled)

    cast_hidden<<<4096, 256, 0, stream>>>(hs, hsb, 4096 * 1024);
    dim3 tb(32, 8);
    transpose_cast<<<dim3(32, 32), tb, 0, stream>>>(wq, wt);
    transpose_cast<<<dim3(32, 32), tb, 0, stream>>>(wk, wt + (1u << 20));
    transpose_cast<<<dim3(32, 32), tb, 0, stream>>>(wv, wt + (2u << 20));
    transpose_cast<<<dim3(32, 32), tb, 0, stream>>>(wo, wot);
    build_bias<<<16, 256, 0, stream>>>(rb, btab);

    gemm128<<<dim3(32, 24), 256, 0, stream>>>(hsb, wt, 1024, 0, qb, kb, vtb, nullptr);
    attn_kernel<<<1024, 256, 0, stream>>>(qb, kb, vtb, btab, out + 4194304, ctxb);
    gemm128<<<dim3(32, 8), 256, 0, stream>>>(ctxb, wot, 1024, 1, nullptr, nullptr, nullptr, out);
}